// Round 17
// baseline (538.593 us; speedup 1.0000x reference)
//
#include <hip/hip_runtime.h>
#include <hip/hip_bf16.h>

#define BB 128   // batch
#define TT 512   // time
#define EE 100   // embed dim
#define HH 128   // hidden
#define KK 12    // tags
#define VV 50257 // vocab
#define NB 8     // batches per block (recurrent)
#define NBLK 16  // recurrent blocks

typedef short bf16x8 __attribute__((ext_vector_type(8)));
typedef float f32x4  __attribute__((ext_vector_type(4)));

__device__ __forceinline__ unsigned short f2bf(float x) {
  __hip_bfloat16 h = __float2bfloat16(x);
  return *reinterpret_cast<unsigned short*>(&h);
}
__device__ __forceinline__ float bf2f(unsigned short u) {
  return __uint_as_float(((unsigned)u) << 16);
}

__device__ __forceinline__ bf16x8 load8_bf(const float* p) {
  float4 a = *reinterpret_cast<const float4*>(p);
  float4 b = *reinterpret_cast<const float4*>(p + 4);
  bf16x8 r;
  r[0] = (short)f2bf(a.x); r[1] = (short)f2bf(a.y);
  r[2] = (short)f2bf(a.z); r[3] = (short)f2bf(a.w);
  r[4] = (short)f2bf(b.x); r[5] = (short)f2bf(b.y);
  r[6] = (short)f2bf(b.z); r[7] = (short)f2bf(b.w);
  return r;
}

// Wih fragment chunk with bias folded at k==EE, zeros past
__device__ __forceinline__ bf16x8 load8_bf_pad_bias(const float* row, int k0,
                                                    float bias) {
  bf16x8 r;
  #pragma unroll
  for (int i = 0; i < 8; ++i) {
    int k = k0 + i;
    unsigned short v = 0;
    if (k < EE) v = f2bf(row[k]);
    else if (k == EE) v = f2bf(bias);
    r[i] = (short)v;
  }
  return r;
}

// ushort index of (row b, col k) in A-frag-ordered tile (lane-linear)
__device__ __forceinline__ int frag_idx(int b, int k) {
  return ((k >> 5) << 9) + ((b + (((k >> 3) & 3) << 4)) << 3) + (k & 7);
}

// LDS-only barrier: waits DS ops, leaves global loads/stores in flight.
__device__ __forceinline__ void lds_barrier() {
  asm volatile("s_waitcnt lgkmcnt(0)\n\ts_barrier" ::: "memory");
}

// ---------------------------------------------------------------------------
// Kernel 0: wprep: Wih -> B-fragment table wbf[s8][tt][kt][lane] (bf16x8).
// gate col = tt*128 + 16*s8 + (l&15); k0 = kt*32 + (l>>4)*8; bias at k==100.
// ---------------------------------------------------------------------------
__global__ __launch_bounds__(256) void wprep_kernel(
    const float* __restrict__ Wih, const float* __restrict__ bih,
    const float* __restrict__ bhh, unsigned short* __restrict__ wbf)
{
  int id = blockIdx.x * 256 + threadIdx.x;   // 8192 frags
  if (id >= 8 * 4 * 4 * 64) return;
  int l = id & 63, kt = (id >> 6) & 3, tt = (id >> 8) & 3, s8 = id >> 10;
  int gcol = tt * HH + 16 * s8 + (l & 15);
  int k0 = kt * 32 + (l >> 4) * 8;
  float bias = bih[gcol] + bhh[gcol];
  bf16x8 r = load8_bf_pad_bias(Wih + (size_t)gcol * EE, k0, bias);
  *reinterpret_cast<bf16x8*>(wbf + (size_t)id * 8) = r;
}

// ---------------------------------------------------------------------------
// Kernel 1: pregates GEMM, reading fp32 embed DIRECTLY (no precast table).
// A-row = embed[sent[b,t]] bf16-converted in-register; k==100 bias slot = 1.0.
// P16[flat(b,t)][e][tt] bf16 quad-interleaved.
// ---------------------------------------------------------------------------
__global__ __launch_bounds__(256, 2) void pregates_kernel(
    const int* __restrict__ sent, const float* __restrict__ embed,
    const unsigned short* __restrict__ wbf, unsigned short* __restrict__ P16)
{
  const int w = threadIdx.x >> 6, l = threadIdx.x & 63;
  const int c = l & 15, q = l >> 4;
  const int rt = blockIdx.x * 4 + w;
  const int flat = rt * 16 + c;               // this lane's A row
  const int b = flat >> 9, t = flat & 511;
  const int id = sent[b * TT + t];
  const float* er = embed + (size_t)id * EE;

  bf16x8 xa[4];
  #pragma unroll
  for (int kt = 0; kt < 3; ++kt)
    xa[kt] = load8_bf(er + kt * 32 + q * 8);  // k <= 95 < 100: all valid
  {
    bf16x8 r;
    #pragma unroll
    for (int i = 0; i < 8; ++i) r[i] = 0;
    if (q == 0) {                             // k = 96..103
      float4 a = *reinterpret_cast<const float4*>(er + 96);
      r[0] = (short)f2bf(a.x); r[1] = (short)f2bf(a.y);
      r[2] = (short)f2bf(a.z); r[3] = (short)f2bf(a.w);
      r[4] = (short)0x3F80;                   // k==100 bias slot = 1.0
    }
    xa[3] = r;                                // q>=1: k >= 104 -> zeros
  }

  const bf16x8* wb = reinterpret_cast<const bf16x8*>(wbf);
  #pragma unroll
  for (int s8 = 0; s8 < 8; ++s8) {
    f32x4 acc[4];
    #pragma unroll
    for (int tt = 0; tt < 4; ++tt) {
      f32x4 z = {0.f, 0.f, 0.f, 0.f};
      acc[tt] = z;
    }
    #pragma unroll
    for (int kt = 0; kt < 4; ++kt) {
      #pragma unroll
      for (int tt = 0; tt < 4; ++tt)
        acc[tt] = __builtin_amdgcn_mfma_f32_16x16x32_bf16(
            xa[kt], wb[((s8 * 4 + tt) * 4 + kt) * 64 + l], acc[tt], 0, 0, 0);
    }
    const int e = s8 * 16 + c;
    #pragma unroll
    for (int r4 = 0; r4 < 4; ++r4) {
      int fr = rt * 16 + q * 4 + r4;          // D row = (l>>4)*4 + reg
      ushort4 o = make_ushort4(f2bf(acc[0][r4]), f2bf(acc[1][r4]),
                               f2bf(acc[2][r4]), f2bf(acc[3][r4]));
      *reinterpret_cast<ushort4*>(P16 + ((size_t)fr * 128 + e) * 4) = o;
    }
  }
}

// ---------------------------------------------------------------------------
// Kernel 2: PURE recurrent LSTM. Identical to round 16 EXCEPT: lanes whose
// A-row is a permanently-zero garbage row (c & 2 != 0 -> rows q*4+{2,3})
// SKIP the ds_read entirely (regs pre-zeroed) -> LDS port reads go from
// 64-lane to 32-lane instructions, halving the A-broadcast port time.
// ---------------------------------------------------------------------------
__global__ __launch_bounds__(512, 2) void lstm_kernel(
    const unsigned short* __restrict__ P16, const float* __restrict__ Whh,
    const float* __restrict__ h0, const float* __restrict__ c0,
    unsigned short* __restrict__ hst)
{
  __shared__ __align__(16) unsigned short hfrag[2][2048];  // 8 KB h, frag order
  __shared__ __align__(16) unsigned int lpad[19456];       // 76 KB placement pad

  const int bg  = blockIdx.x;
  const int tid = threadIdx.x;
  const int w   = tid >> 6;
  const int l   = tid & 63;
  const int c   = l & 15;
  const int q   = l >> 4;
  const int ew  = 16 * w + c;
  const bool arow = ((c & 2) == 0);   // A-row c holds a real batch

  bf16x8 wh[4][4];
  #pragma unroll
  for (int tt = 0; tt < 4; ++tt) {
    const int gcol = tt * HH + ew;
    #pragma unroll
    for (int kt = 0; kt < 4; ++kt)
      wh[tt][kt] = load8_bf(Whh + (size_t)gcol * HH + kt * 32 + q * 8);
  }

  float cst[2];
  #pragma unroll
  for (int r = 0; r < 2; ++r)
    cst[r] = c0[(size_t)(bg * NB + q * 2 + r) * HH + ew];

  {
    int4 z = {0, 0, 0, 0};
    reinterpret_cast<int4*>(hfrag)[tid] = z;
  }
  for (int i = tid; i < 19456; i += 512) lpad[i] = 0u;
  unsigned int keep = lpad[tid];
  asm volatile("" :: "v"(keep));
  __syncthreads();

  for (int idx = tid; idx < NB * HH; idx += 512) {
    int lb = idx >> 7, k = idx & 127;
    int row = ((lb >> 1) << 2) + (lb & 1);
    hfrag[0][frag_idx(row, k)] = f2bf(h0[(size_t)(bg * NB + lb) * HH + k]);
  }

  const unsigned short* pb0 =
      P16 + (size_t)(bg * NB + q * 2 + 0) * (TT * 512) + ew * 4;
  const unsigned short* pb1 =
      P16 + (size_t)(bg * NB + q * 2 + 1) * (TT * 512) + ew * 4;
  ushort4 pA[2], pB[2];
  pA[0] = *reinterpret_cast<const ushort4*>(pb0);
  pA[1] = *reinterpret_cast<const ushort4*>(pb1);
  pB[0] = *reinterpret_cast<const ushort4*>(pb0 + 512);
  pB[1] = *reinterpret_cast<const ushort4*>(pb1 + 512);

  unsigned short hp[2] = {0, 0};
  unsigned short* hb0 = hst + (size_t)(bg * NB + q * 2 + 0) * TT * HH + ew;
  unsigned short* hb1 = hst + (size_t)(bg * NB + q * 2 + 1) * TT * HH + ew;

  const int hw_off = frag_idx(q * 4, ew);
  __syncthreads();

  auto step = [&](int s, ushort4 (&pcur)[2]) {
    const int rb = s & 1;

    if (s >= 1 && s <= TT) {
      hb0[(size_t)(s - 1) * HH] = hp[0];
      hb1[(size_t)(s - 1) * HH] = hp[1];
    }

    if (s < TT) {
      // A-frags: garbage rows (c&2) are permanently zero -> skip their reads
      bf16x8 ha[4];
      #pragma unroll
      for (int kt = 0; kt < 4; ++kt) {
        #pragma unroll
        for (int i = 0; i < 8; ++i) ha[kt][i] = 0;
      }
      if (arow) {
        const bf16x8* hr = reinterpret_cast<const bf16x8*>(&hfrag[rb][0]) + l;
        #pragma unroll
        for (int kt = 0; kt < 4; ++kt) ha[kt] = hr[kt * 64];
      }

      f32x4 acc[4];
      #pragma unroll
      for (int tt = 0; tt < 4; ++tt) {
        f32x4 z = {0.f, 0.f, 0.f, 0.f};
        acc[tt] = z;
      }
      acc[0][0] = bf2f(pcur[0].x); acc[1][0] = bf2f(pcur[0].y);
      acc[2][0] = bf2f(pcur[0].z); acc[3][0] = bf2f(pcur[0].w);
      acc[0][1] = bf2f(pcur[1].x); acc[1][1] = bf2f(pcur[1].y);
      acc[2][1] = bf2f(pcur[1].z); acc[3][1] = bf2f(pcur[1].w);

      if (s + 2 < TT) {
        pcur[0] = *reinterpret_cast<const ushort4*>(pb0 + (size_t)(s + 2) * 512);
        pcur[1] = *reinterpret_cast<const ushort4*>(pb1 + (size_t)(s + 2) * 512);
      }

      #pragma unroll
      for (int kt = 0; kt < 4; ++kt) {
        #pragma unroll
        for (int tt = 0; tt < 4; ++tt)
          acc[tt] = __builtin_amdgcn_mfma_f32_16x16x32_bf16(ha[kt], wh[tt][kt], acc[tt], 0, 0, 0);
      }

      unsigned short* hwp = &hfrag[rb ^ 1][hw_off];
      #pragma unroll
      for (int r = 0; r < 2; ++r) {
        float ai  = __builtin_amdgcn_exp2f(acc[0][r] * -1.44269504f);
        float bgg = __builtin_amdgcn_exp2f(acc[2][r] * -2.88539008f);
        float af  = __builtin_amdgcn_exp2f(acc[1][r] * -1.44269504f);
        float ao  = __builtin_amdgcn_exp2f(acc[3][r] * -1.44269504f);
        float sitg = (1.0f - bgg) *
                     __builtin_amdgcn_rcpf((1.0f + ai) * (1.0f + bgg));
        float sf = __builtin_amdgcn_rcpf(1.0f + af);
        cst[r] = __fmaf_rn(sf, cst[r], sitg);
        float cc = __builtin_amdgcn_fmed3f(cst[r], -30.0f, 30.0f);
        float ec = __builtin_amdgcn_exp2f(cc * -2.88539008f);
        float hv = (1.0f - ec) *
                   __builtin_amdgcn_rcpf((1.0f + ao) * (1.0f + ec));
        unsigned short hu = f2bf(hv);
        hwp[r * 8] = hu;
        hp[r] = hu;
      }
    }
    lds_barrier();
  };

  for (int s = 0; s < TT + 2; s += 2) {
    step(s, pA);
    step(s + 1, pB);
  }
}

// ---------------------------------------------------------------------------
// Kernel 3: fused emissions + Viterbi + backtrace, barrier-free (1 wave).
// Identical to round 16.
// ---------------------------------------------------------------------------
__global__ __launch_bounds__(64) void vit_kernel(
    const unsigned short* __restrict__ hst, const float* __restrict__ Wtag,
    const float* __restrict__ btag, const float* __restrict__ trans,
    float* __restrict__ out)
{
  __shared__ __align__(16) float ering[2][16 * 16];
  __shared__ unsigned char bp[TT * KK];          // 6 KB backpointers
  __shared__ unsigned char path[TT];

  const int b = blockIdx.x, tid = threadIdx.x;   // 64 threads = 1 wave
  const int c = tid & 15, q = tid >> 4;
  const int j = tid;                             // DP tag lane (j<12 active)

  float trl_r[KK];
  #pragma unroll
  for (int i = 0; i < KK; ++i)
    trl_r[i] = (j < KK) ? trans[i * KK + j] : 0.f;

  bf16x8 we[4];
  #pragma unroll
  for (int kt = 0; kt < 4; ++kt) {
    #pragma unroll
    for (int i = 0; i < 8; ++i) we[kt][i] = 0;
  }
  float bt = 0.f;
  if (c < KK) {
    #pragma unroll
    for (int kt = 0; kt < 4; ++kt)
      we[kt] = load8_bf(Wtag + (size_t)c * HH + kt * 32 + q * 8);
    bt = btag[c];
  }
  const unsigned short* hb = hst + (size_t)b * TT * HH;

  bf16x8 ha[4];
  #pragma unroll
  for (int kt = 0; kt < 4; ++kt)
    ha[kt] = *reinterpret_cast<const bf16x8*>(
        hb + (size_t)c * HH + kt * 32 + q * 8);

  float v = 0.f;

  for (int tb = 0; tb < TT; tb += 16) {
    const int par = (tb >> 4) & 1;

    f32x4 accE = {0.f, 0.f, 0.f, 0.f};
    #pragma unroll
    for (int kt = 0; kt < 4; ++kt)
      accE = __builtin_amdgcn_mfma_f32_16x16x32_bf16(ha[kt], we[kt], accE, 0, 0, 0);
    #pragma unroll
    for (int r = 0; r < 4; ++r)
      ering[par][(q * 4 + r) * 16 + c] = accE[r] + bt;

    if (tb + 16 < TT) {
      #pragma unroll
      for (int kt = 0; kt < 4; ++kt)
        ha[kt] = *reinterpret_cast<const bf16x8*>(
            hb + (size_t)(tb + 16 + c) * HH + kt * 32 + q * 8);
    }

    float er[16];
    #pragma unroll
    for (int i = 0; i < 16; ++i) er[i] = ering[par][i * 16 + (j & 15)];

    #pragma unroll
    for (int i = 0; i < 16; ++i) {
      const int t = tb + i;
      float vv[KK];
      #pragma unroll
      for (int i2 = 0; i2 < KK; ++i2) vv[i2] = __shfl(v, i2);
      if (t == 0) {
        v = er[0];
      } else {
        float cand[KK];
        #pragma unroll
        for (int i2 = 0; i2 < KK; ++i2) cand[i2] = vv[i2] + trl_r[i2];
        float g0 = fmaxf(fmaxf(cand[0], cand[1]), cand[2]);
        float g1 = fmaxf(fmaxf(cand[3], cand[4]), cand[5]);
        float g2 = fmaxf(fmaxf(cand[6], cand[7]), cand[8]);
        float g3 = fmaxf(fmaxf(cand[9], cand[10]), cand[11]);
        float best = fmaxf(fmaxf(g0, g1), fmaxf(g2, g3));
        int bi = 11;
        #pragma unroll
        for (int k = 10; k >= 0; --k) bi = (cand[k] == best) ? k : bi;
        v = er[i] + best;
        if (j < KK) bp[t * KK + j] = (unsigned char)bi;
      }
    }
  }

  float vv[KK];
  #pragma unroll
  for (int i2 = 0; i2 < KK; ++i2) vv[i2] = __shfl(v, i2);
  float best = vv[0];
  int tag = 0;
  #pragma unroll
  for (int i2 = 1; i2 < KK; ++i2)
    if (vv[i2] > best) { best = vv[i2]; tag = i2; }
  if (tid == 0) {
    out[b] = best;
    path[TT - 1] = (unsigned char)tag;
  }

  for (int tb = TT - 64; tb >= 0; tb -= 64) {
    const unsigned* bpw =
        reinterpret_cast<const unsigned*>(bp + (size_t)(tb + tid) * KK);
    unsigned r0 = bpw[0], r1 = bpw[1], r2 = bpw[2];
    #pragma unroll
    for (int i = 63; i >= 0; --i) {
      const int t = tb + i;
      if (t >= 1) {
        unsigned d0 = __shfl(r0, i), d1 = __shfl(r1, i), d2 = __shfl(r2, i);
        unsigned d = (tag < 4) ? d0 : ((tag < 8) ? d1 : d2);
        tag = (int)((d >> ((tag & 3) * 8)) & 0xffu);
        if (tid == 0) path[t - 1] = (unsigned char)tag;
      }
    }
  }

  #pragma unroll
  for (int i = 0; i < 8; ++i)
    out[BB + (size_t)b * TT + tid + i * 64] = (float)path[tid + i * 64];
}

// ---------------------------------------------------------------------------
extern "C" void kernel_launch(void* const* d_in, const int* in_sizes, int n_in,
                              void* d_out, int out_size, void* d_ws, size_t ws_size,
                              hipStream_t stream) {
  const int*   sent  = (const int*)d_in[0];
  const float* h0    = (const float*)d_in[1];
  const float* c0    = (const float*)d_in[2];
  const float* embed = (const float*)d_in[3];
  const float* Wih   = (const float*)d_in[4];
  const float* Whh   = (const float*)d_in[5];
  const float* bih   = (const float*)d_in[6];
  const float* bhh   = (const float*)d_in[7];
  const float* Wtag  = (const float*)d_in[8];
  const float* btag  = (const float*)d_in[9];
  const float* trans = (const float*)d_in[10];
  float* out = (float*)d_out;

  // workspace: wbf 128KB | P16 64MB | hst 16MB   (~80MB)
  unsigned short* wbf = (unsigned short*)d_ws;
  unsigned short* P16 = wbf + 8192 * 8;
  unsigned short* hst = P16 + (size_t)BB * TT * 512;

  wprep_kernel<<<32, 256, 0, stream>>>(Wih, bih, bhh, wbf);
  pregates_kernel<<<(BB * TT / 16) / 4, 256, 0, stream>>>(sent, embed, wbf, P16);
  lstm_kernel<<<NBLK, 512, 0, stream>>>(P16, Whh, h0, c0, hst);
  vit_kernel<<<BB, 64, 0, stream>>>(hst, Wtag, btag, trans, out);
}

// Round 18
// 505.668 us; speedup vs baseline: 1.0651x; 1.0651x over previous
//
#include <hip/hip_runtime.h>
#include <hip/hip_bf16.h>

#define BB 128   // batch
#define TT 512   // time
#define EE 100   // embed dim
#define HH 128   // hidden
#define KK 12    // tags
#define VV 50257 // vocab
#define NB 8     // batches per block (recurrent)
#define NBLK 16  // recurrent blocks

typedef short bf16x8 __attribute__((ext_vector_type(8)));
typedef float f32x4  __attribute__((ext_vector_type(4)));

__device__ __forceinline__ unsigned short f2bf(float x) {
  __hip_bfloat16 h = __float2bfloat16(x);
  return *reinterpret_cast<unsigned short*>(&h);
}
__device__ __forceinline__ float bf2f(unsigned short u) {
  return __uint_as_float(((unsigned)u) << 16);
}

__device__ __forceinline__ bf16x8 load8_bf(const float* p) {
  float4 a = *reinterpret_cast<const float4*>(p);
  float4 b = *reinterpret_cast<const float4*>(p + 4);
  bf16x8 r;
  r[0] = (short)f2bf(a.x); r[1] = (short)f2bf(a.y);
  r[2] = (short)f2bf(a.z); r[3] = (short)f2bf(a.w);
  r[4] = (short)f2bf(b.x); r[5] = (short)f2bf(b.y);
  r[6] = (short)f2bf(b.z); r[7] = (short)f2bf(b.w);
  return r;
}

// Wih fragment chunk with bias folded at k==EE, zeros past
__device__ __forceinline__ bf16x8 load8_bf_pad_bias(const float* row, int k0,
                                                    float bias) {
  bf16x8 r;
  #pragma unroll
  for (int i = 0; i < 8; ++i) {
    int k = k0 + i;
    unsigned short v = 0;
    if (k < EE) v = f2bf(row[k]);
    else if (k == EE) v = f2bf(bias);
    r[i] = (short)v;
  }
  return r;
}

// ushort index of (row b, col k) in A-frag-ordered tile (lane-linear)
__device__ __forceinline__ int frag_idx(int b, int k) {
  return ((k >> 5) << 9) + ((b + (((k >> 3) & 3) << 4)) << 3) + (k & 7);
}

// LDS-only barrier: waits DS ops, leaves global loads/stores in flight.
__device__ __forceinline__ void lds_barrier() {
  asm volatile("s_waitcnt lgkmcnt(0)\n\ts_barrier" ::: "memory");
}

// ---------------------------------------------------------------------------
// Kernel 0: wprep: Wih -> B-fragment table wbf[s8][tt][kt][lane] (bf16x8).
// gate col = tt*128 + 16*s8 + (l&15); k0 = kt*32 + (l>>4)*8; bias at k==100.
// ---------------------------------------------------------------------------
__global__ __launch_bounds__(256) void wprep_kernel(
    const float* __restrict__ Wih, const float* __restrict__ bih,
    const float* __restrict__ bhh, unsigned short* __restrict__ wbf)
{
  int id = blockIdx.x * 256 + threadIdx.x;   // 8192 frags
  if (id >= 8 * 4 * 4 * 64) return;
  int l = id & 63, kt = (id >> 6) & 3, tt = (id >> 8) & 3, s8 = id >> 10;
  int gcol = tt * HH + 16 * s8 + (l & 15);
  int k0 = kt * 32 + (l >> 4) * 8;
  float bias = bih[gcol] + bhh[gcol];
  bf16x8 r = load8_bf_pad_bias(Wih + (size_t)gcol * EE, k0, bias);
  *reinterpret_cast<bf16x8*>(wbf + (size_t)id * 8) = r;
}

// ---------------------------------------------------------------------------
// Kernel 1: pregates GEMM, reading fp32 embed DIRECTLY (no precast table).
// A-row = embed[sent[b,t]] bf16-converted in-register; k==100 bias slot = 1.0.
// P16[flat(b,t)][e][tt] bf16 quad-interleaved.
// ---------------------------------------------------------------------------
__global__ __launch_bounds__(256, 2) void pregates_kernel(
    const int* __restrict__ sent, const float* __restrict__ embed,
    const unsigned short* __restrict__ wbf, unsigned short* __restrict__ P16)
{
  const int w = threadIdx.x >> 6, l = threadIdx.x & 63;
  const int c = l & 15, q = l >> 4;
  const int rt = blockIdx.x * 4 + w;
  const int flat = rt * 16 + c;               // this lane's A row
  const int b = flat >> 9, t = flat & 511;
  const int id = sent[b * TT + t];
  const float* er = embed + (size_t)id * EE;

  bf16x8 xa[4];
  #pragma unroll
  for (int kt = 0; kt < 3; ++kt)
    xa[kt] = load8_bf(er + kt * 32 + q * 8);  // k <= 95 < 100: all valid
  {
    bf16x8 r;
    #pragma unroll
    for (int i = 0; i < 8; ++i) r[i] = 0;
    if (q == 0) {                             // k = 96..103
      float4 a = *reinterpret_cast<const float4*>(er + 96);
      r[0] = (short)f2bf(a.x); r[1] = (short)f2bf(a.y);
      r[2] = (short)f2bf(a.z); r[3] = (short)f2bf(a.w);
      r[4] = (short)0x3F80;                   // k==100 bias slot = 1.0
    }
    xa[3] = r;                                // q>=1: k >= 104 -> zeros
  }

  const bf16x8* wb = reinterpret_cast<const bf16x8*>(wbf);
  #pragma unroll
  for (int s8 = 0; s8 < 8; ++s8) {
    f32x4 acc[4];
    #pragma unroll
    for (int tt = 0; tt < 4; ++tt) {
      f32x4 z = {0.f, 0.f, 0.f, 0.f};
      acc[tt] = z;
    }
    #pragma unroll
    for (int kt = 0; kt < 4; ++kt) {
      #pragma unroll
      for (int tt = 0; tt < 4; ++tt)
        acc[tt] = __builtin_amdgcn_mfma_f32_16x16x32_bf16(
            xa[kt], wb[((s8 * 4 + tt) * 4 + kt) * 64 + l], acc[tt], 0, 0, 0);
    }
    const int e = s8 * 16 + c;
    #pragma unroll
    for (int r4 = 0; r4 < 4; ++r4) {
      int fr = rt * 16 + q * 4 + r4;          // D row = (l>>4)*4 + reg
      ushort4 o = make_ushort4(f2bf(acc[0][r4]), f2bf(acc[1][r4]),
                               f2bf(acc[2][r4]), f2bf(acc[3][r4]));
      *reinterpret_cast<ushort4*>(P16 + ((size_t)fr * 128 + e) * 4) = o;
    }
  }
}

// ---------------------------------------------------------------------------
// Kernel 2: PURE recurrent LSTM — round 16's exact loop (unmasked A-reads,
// the measured-best variant: 342 us). Per step: ds_read(ha) -> P-quad acc
// init -> 16 MFMA -> merged-rcp activations -> ds_write(h) -> LDS barrier.
// ---------------------------------------------------------------------------
__global__ __launch_bounds__(512, 2) void lstm_kernel(
    const unsigned short* __restrict__ P16, const float* __restrict__ Whh,
    const float* __restrict__ h0, const float* __restrict__ c0,
    unsigned short* __restrict__ hst)
{
  __shared__ __align__(16) unsigned short hfrag[2][2048];  // 8 KB h, frag order
  __shared__ __align__(16) unsigned int lpad[19456];       // 76 KB placement pad

  const int bg  = blockIdx.x;
  const int tid = threadIdx.x;
  const int w   = tid >> 6;
  const int l   = tid & 63;
  const int c   = l & 15;
  const int q   = l >> 4;
  const int ew  = 16 * w + c;

  bf16x8 wh[4][4];
  #pragma unroll
  for (int tt = 0; tt < 4; ++tt) {
    const int gcol = tt * HH + ew;
    #pragma unroll
    for (int kt = 0; kt < 4; ++kt)
      wh[tt][kt] = load8_bf(Whh + (size_t)gcol * HH + kt * 32 + q * 8);
  }

  float cst[2];
  #pragma unroll
  for (int r = 0; r < 2; ++r)
    cst[r] = c0[(size_t)(bg * NB + q * 2 + r) * HH + ew];

  {
    int4 z = {0, 0, 0, 0};
    reinterpret_cast<int4*>(hfrag)[tid] = z;
  }
  for (int i = tid; i < 19456; i += 512) lpad[i] = 0u;
  unsigned int keep = lpad[tid];
  asm volatile("" :: "v"(keep));
  __syncthreads();

  for (int idx = tid; idx < NB * HH; idx += 512) {
    int lb = idx >> 7, k = idx & 127;
    int row = ((lb >> 1) << 2) + (lb & 1);
    hfrag[0][frag_idx(row, k)] = f2bf(h0[(size_t)(bg * NB + lb) * HH + k]);
  }

  const unsigned short* pb0 =
      P16 + (size_t)(bg * NB + q * 2 + 0) * (TT * 512) + ew * 4;
  const unsigned short* pb1 =
      P16 + (size_t)(bg * NB + q * 2 + 1) * (TT * 512) + ew * 4;
  ushort4 pA[2], pB[2];
  pA[0] = *reinterpret_cast<const ushort4*>(pb0);
  pA[1] = *reinterpret_cast<const ushort4*>(pb1);
  pB[0] = *reinterpret_cast<const ushort4*>(pb0 + 512);
  pB[1] = *reinterpret_cast<const ushort4*>(pb1 + 512);

  unsigned short hp[2] = {0, 0};
  unsigned short* hb0 = hst + (size_t)(bg * NB + q * 2 + 0) * TT * HH + ew;
  unsigned short* hb1 = hst + (size_t)(bg * NB + q * 2 + 1) * TT * HH + ew;

  const int hw_off = frag_idx(q * 4, ew);
  __syncthreads();

  auto step = [&](int s, ushort4 (&pcur)[2]) {
    const int rb = s & 1;

    if (s >= 1 && s <= TT) {
      hb0[(size_t)(s - 1) * HH] = hp[0];
      hb1[(size_t)(s - 1) * HH] = hp[1];
    }

    if (s < TT) {
      bf16x8 ha[4];
      const bf16x8* hr = reinterpret_cast<const bf16x8*>(&hfrag[rb][0]) + l;
      #pragma unroll
      for (int kt = 0; kt < 4; ++kt) ha[kt] = hr[kt * 64];

      f32x4 acc[4];
      #pragma unroll
      for (int tt = 0; tt < 4; ++tt) {
        f32x4 z = {0.f, 0.f, 0.f, 0.f};
        acc[tt] = z;
      }
      acc[0][0] = bf2f(pcur[0].x); acc[1][0] = bf2f(pcur[0].y);
      acc[2][0] = bf2f(pcur[0].z); acc[3][0] = bf2f(pcur[0].w);
      acc[0][1] = bf2f(pcur[1].x); acc[1][1] = bf2f(pcur[1].y);
      acc[2][1] = bf2f(pcur[1].z); acc[3][1] = bf2f(pcur[1].w);

      if (s + 2 < TT) {
        pcur[0] = *reinterpret_cast<const ushort4*>(pb0 + (size_t)(s + 2) * 512);
        pcur[1] = *reinterpret_cast<const ushort4*>(pb1 + (size_t)(s + 2) * 512);
      }

      #pragma unroll
      for (int kt = 0; kt < 4; ++kt) {
        #pragma unroll
        for (int tt = 0; tt < 4; ++tt)
          acc[tt] = __builtin_amdgcn_mfma_f32_16x16x32_bf16(ha[kt], wh[tt][kt], acc[tt], 0, 0, 0);
      }

      unsigned short* hwp = &hfrag[rb ^ 1][hw_off];
      #pragma unroll
      for (int r = 0; r < 2; ++r) {
        float ai  = __builtin_amdgcn_exp2f(acc[0][r] * -1.44269504f);
        float bgg = __builtin_amdgcn_exp2f(acc[2][r] * -2.88539008f);
        float af  = __builtin_amdgcn_exp2f(acc[1][r] * -1.44269504f);
        float ao  = __builtin_amdgcn_exp2f(acc[3][r] * -1.44269504f);
        float sitg = (1.0f - bgg) *
                     __builtin_amdgcn_rcpf((1.0f + ai) * (1.0f + bgg));
        float sf = __builtin_amdgcn_rcpf(1.0f + af);
        cst[r] = __fmaf_rn(sf, cst[r], sitg);
        float cc = __builtin_amdgcn_fmed3f(cst[r], -30.0f, 30.0f);
        float ec = __builtin_amdgcn_exp2f(cc * -2.88539008f);
        float hv = (1.0f - ec) *
                   __builtin_amdgcn_rcpf((1.0f + ao) * (1.0f + ec));
        unsigned short hu = f2bf(hv);
        hwp[r * 8] = hu;
        hp[r] = hu;
      }
    }
    lds_barrier();
  };

  for (int s = 0; s < TT + 2; s += 2) {
    step(s, pA);
    step(s + 1, pB);
  }
}

// ---------------------------------------------------------------------------
// Kernel 3: fused emissions + Viterbi + backtrace, barrier-free (1 wave).
// Identical to round 16.
// ---------------------------------------------------------------------------
__global__ __launch_bounds__(64) void vit_kernel(
    const unsigned short* __restrict__ hst, const float* __restrict__ Wtag,
    const float* __restrict__ btag, const float* __restrict__ trans,
    float* __restrict__ out)
{
  __shared__ __align__(16) float ering[2][16 * 16];
  __shared__ unsigned char bp[TT * KK];          // 6 KB backpointers
  __shared__ unsigned char path[TT];

  const int b = blockIdx.x, tid = threadIdx.x;   // 64 threads = 1 wave
  const int c = tid & 15, q = tid >> 4;
  const int j = tid;                             // DP tag lane (j<12 active)

  float trl_r[KK];
  #pragma unroll
  for (int i = 0; i < KK; ++i)
    trl_r[i] = (j < KK) ? trans[i * KK + j] : 0.f;

  bf16x8 we[4];
  #pragma unroll
  for (int kt = 0; kt < 4; ++kt) {
    #pragma unroll
    for (int i = 0; i < 8; ++i) we[kt][i] = 0;
  }
  float bt = 0.f;
  if (c < KK) {
    #pragma unroll
    for (int kt = 0; kt < 4; ++kt)
      we[kt] = load8_bf(Wtag + (size_t)c * HH + kt * 32 + q * 8);
    bt = btag[c];
  }
  const unsigned short* hb = hst + (size_t)b * TT * HH;

  bf16x8 ha[4];
  #pragma unroll
  for (int kt = 0; kt < 4; ++kt)
    ha[kt] = *reinterpret_cast<const bf16x8*>(
        hb + (size_t)c * HH + kt * 32 + q * 8);

  float v = 0.f;

  for (int tb = 0; tb < TT; tb += 16) {
    const int par = (tb >> 4) & 1;

    f32x4 accE = {0.f, 0.f, 0.f, 0.f};
    #pragma unroll
    for (int kt = 0; kt < 4; ++kt)
      accE = __builtin_amdgcn_mfma_f32_16x16x32_bf16(ha[kt], we[kt], accE, 0, 0, 0);
    #pragma unroll
    for (int r = 0; r < 4; ++r)
      ering[par][(q * 4 + r) * 16 + c] = accE[r] + bt;

    if (tb + 16 < TT) {
      #pragma unroll
      for (int kt = 0; kt < 4; ++kt)
        ha[kt] = *reinterpret_cast<const bf16x8*>(
            hb + (size_t)(tb + 16 + c) * HH + kt * 32 + q * 8);
    }

    float er[16];
    #pragma unroll
    for (int i = 0; i < 16; ++i) er[i] = ering[par][i * 16 + (j & 15)];

    #pragma unroll
    for (int i = 0; i < 16; ++i) {
      const int t = tb + i;
      float vv[KK];
      #pragma unroll
      for (int i2 = 0; i2 < KK; ++i2) vv[i2] = __shfl(v, i2);
      if (t == 0) {
        v = er[0];
      } else {
        float cand[KK];
        #pragma unroll
        for (int i2 = 0; i2 < KK; ++i2) cand[i2] = vv[i2] + trl_r[i2];
        float g0 = fmaxf(fmaxf(cand[0], cand[1]), cand[2]);
        float g1 = fmaxf(fmaxf(cand[3], cand[4]), cand[5]);
        float g2 = fmaxf(fmaxf(cand[6], cand[7]), cand[8]);
        float g3 = fmaxf(fmaxf(cand[9], cand[10]), cand[11]);
        float best = fmaxf(fmaxf(g0, g1), fmaxf(g2, g3));
        int bi = 11;
        #pragma unroll
        for (int k = 10; k >= 0; --k) bi = (cand[k] == best) ? k : bi;
        v = er[i] + best;
        if (j < KK) bp[t * KK + j] = (unsigned char)bi;
      }
    }
  }

  float vv[KK];
  #pragma unroll
  for (int i2 = 0; i2 < KK; ++i2) vv[i2] = __shfl(v, i2);
  float best = vv[0];
  int tag = 0;
  #pragma unroll
  for (int i2 = 1; i2 < KK; ++i2)
    if (vv[i2] > best) { best = vv[i2]; tag = i2; }
  if (tid == 0) {
    out[b] = best;
    path[TT - 1] = (unsigned char)tag;
  }

  for (int tb = TT - 64; tb >= 0; tb -= 64) {
    const unsigned* bpw =
        reinterpret_cast<const unsigned*>(bp + (size_t)(tb + tid) * KK);
    unsigned r0 = bpw[0], r1 = bpw[1], r2 = bpw[2];
    #pragma unroll
    for (int i = 63; i >= 0; --i) {
      const int t = tb + i;
      if (t >= 1) {
        unsigned d0 = __shfl(r0, i), d1 = __shfl(r1, i), d2 = __shfl(r2, i);
        unsigned d = (tag < 4) ? d0 : ((tag < 8) ? d1 : d2);
        tag = (int)((d >> ((tag & 3) * 8)) & 0xffu);
        if (tid == 0) path[t - 1] = (unsigned char)tag;
      }
    }
  }

  #pragma unroll
  for (int i = 0; i < 8; ++i)
    out[BB + (size_t)b * TT + tid + i * 64] = (float)path[tid + i * 64];
}

// ---------------------------------------------------------------------------
extern "C" void kernel_launch(void* const* d_in, const int* in_sizes, int n_in,
                              void* d_out, int out_size, void* d_ws, size_t ws_size,
                              hipStream_t stream) {
  const int*   sent  = (const int*)d_in[0];
  const float* h0    = (const float*)d_in[1];
  const float* c0    = (const float*)d_in[2];
  const float* embed = (const float*)d_in[3];
  const float* Wih   = (const float*)d_in[4];
  const float* Whh   = (const float*)d_in[5];
  const float* bih   = (const float*)d_in[6];
  const float* bhh   = (const float*)d_in[7];
  const float* Wtag  = (const float*)d_in[8];
  const float* btag  = (const float*)d_in[9];
  const float* trans = (const float*)d_in[10];
  float* out = (float*)d_out;

  // workspace: wbf 128KB | P16 64MB | hst 16MB   (~80MB)
  unsigned short* wbf = (unsigned short*)d_ws;
  unsigned short* P16 = wbf + 8192 * 8;
  unsigned short* hst = P16 + (size_t)BB * TT * 512;

  wprep_kernel<<<32, 256, 0, stream>>>(Wih, bih, bhh, wbf);
  pregates_kernel<<<(BB * TT / 16) / 4, 256, 0, stream>>>(sent, embed, wbf, P16);
  lstm_kernel<<<NBLK, 512, 0, stream>>>(P16, Whh, h0, c0, hst);
  vit_kernel<<<BB, 64, 0, stream>>>(hst, Wtag, btag, trans, out);
}